// Round 8
// baseline (171.034 us; speedup 1.0000x reference)
//
#include <hip/hip_runtime.h>
#include <stdint.h>

#define N_COLS 8192
#define N_ROWS 8192
#define C4 (N_COLS / 4)
#define FP8_MAX_F 448.0f
#define EPS_F 1e-12f
#define ROWCHUNKS 128
#define ROWS_PER_BLOCK (N_ROWS / ROWCHUNKS)   // 64
#define QBLOCKS 2048

// ---------------------------------------------------------------------------
// Pass 1: per-(rowchunk, column) partial abs-max. No atomics, no init needed.
// grid (8, 128) x 256 threads; each thread owns 4 columns x 64 rows.
// (Round-4 known-good structure.)
// ---------------------------------------------------------------------------
__global__ __launch_bounds__(256) void col_amax_partial(const float4* __restrict__ x4,
                                                        float4* __restrict__ partial4) {
    int c4 = blockIdx.x * 256 + threadIdx.x;
    const float4* p = x4 + (size_t)blockIdx.y * ROWS_PER_BLOCK * C4 + c4;
    uint32_t m0 = 0, m1 = 0, m2 = 0, m3 = 0;   // |x| bit-pattern max == float max
#pragma unroll 8
    for (int r = 0; r < ROWS_PER_BLOCK; ++r) {
        float4 v = p[(size_t)r * C4];
        m0 = max(m0, __float_as_uint(v.x) & 0x7FFFFFFFu);
        m1 = max(m1, __float_as_uint(v.y) & 0x7FFFFFFFu);
        m2 = max(m2, __float_as_uint(v.z) & 0x7FFFFFFFu);
        m3 = max(m3, __float_as_uint(v.w) & 0x7FFFFFFFu);
    }
    float4 o;
    o.x = __uint_as_float(m0);
    o.y = __uint_as_float(m1);
    o.z = __uint_as_float(m2);
    o.w = __uint_as_float(m3);
    partial4[(size_t)blockIdx.y * C4 + c4] = o;
}

// ---------------------------------------------------------------------------
// Pass 2: reduce 128 partials per column; emit bit-exact forward scale
// (IEEE 448/amax, matches numpy) and the dequant inverse (amax/448).
// ---------------------------------------------------------------------------
__global__ __launch_bounds__(256) void scale_from_partials(const float* __restrict__ partial,
                                                           float* __restrict__ scale,
                                                           float* __restrict__ inv) {
    int c = blockIdx.x * 256 + threadIdx.x;
    float a = 0.0f;
#pragma unroll 8
    for (int k = 0; k < ROWCHUNKS; ++k)
        a = fmaxf(a, partial[(size_t)k * N_COLS + c]);
    a = fmaxf(a, EPS_F);
    scale[c] = FP8_MAX_F / a;   // IEEE divide: must be bit-identical to numpy
    inv[c]   = a / FP8_MAX_F;   // dequant multiplier (1-2 ulp vs q/scale: fine)
}

// ---------------------------------------------------------------------------
// Pass 3: scale -> clip -> HW e4m3fn RNE cast -> dequant-multiply.
// ONE change vs round 4 (149.2 us): PLAIN stores instead of non-temporal.
// (nt-load already proven negative in r6; nt-store never isolated — the
// fills/copy ceilings that hit 6.3-7 TB/s use plain stores.)
// ---------------------------------------------------------------------------
__global__ __launch_bounds__(256) void quant_kernel(const float4* __restrict__ x4,
                                                    const float4* __restrict__ scale4,
                                                    const float4* __restrict__ inv4,
                                                    float4* __restrict__ out4) {
    const size_t n4 = (size_t)N_ROWS * C4;
    const size_t T = (size_t)QBLOCKS * 256;          // threads in grid
    const int NCHUNK = (int)(n4 / T);                // 32
    size_t gtid = (size_t)blockIdx.x * 256 + threadIdx.x;
    for (int c = NCHUNK - 1; c >= 0; --c) {
        size_t i = (size_t)c * T + gtid;
        size_t ci = i & (size_t)(C4 - 1);
        float4 s = scale4[ci];
        float4 w = inv4[ci];
        float4 v = x4[i];
        float a0 = fminf(fmaxf(v.x * s.x, -FP8_MAX_F), FP8_MAX_F);
        float a1 = fminf(fmaxf(v.y * s.y, -FP8_MAX_F), FP8_MAX_F);
        float a2 = fminf(fmaxf(v.z * s.z, -FP8_MAX_F), FP8_MAX_F);
        float a3 = fminf(fmaxf(v.w * s.w, -FP8_MAX_F), FP8_MAX_F);
        int p = __builtin_amdgcn_cvt_pk_fp8_f32(a0, a1, 0, false);
        p = __builtin_amdgcn_cvt_pk_fp8_f32(a2, a3, p, true);
        float4 o;
        o.x = __builtin_amdgcn_cvt_f32_fp8(p, 0) * w.x;
        o.y = __builtin_amdgcn_cvt_f32_fp8(p, 1) * w.y;
        o.z = __builtin_amdgcn_cvt_f32_fp8(p, 2) * w.z;
        o.w = __builtin_amdgcn_cvt_f32_fp8(p, 3) * w.w;
        out4[i] = o;
    }
}

extern "C" void kernel_launch(void* const* d_in, const int* in_sizes, int n_in,
                              void* d_out, int out_size, void* d_ws, size_t ws_size,
                              hipStream_t stream) {
    const float* x = (const float*)d_in[0];
    float* out = (float*)d_out;
    // ws: partial (128*8192 f32 = 4 MB) | scale (32 KB) | inv (32 KB)
    float* partial = (float*)d_ws;
    float* scale = (float*)((char*)d_ws + (size_t)ROWCHUNKS * N_COLS * sizeof(float));
    float* inv = scale + N_COLS;

    dim3 g1(N_COLS / 1024, ROWCHUNKS);
    col_amax_partial<<<g1, 256, 0, stream>>>((const float4*)x, (float4*)partial);

    scale_from_partials<<<N_COLS / 256, 256, 0, stream>>>(partial, scale, inv);

    quant_kernel<<<QBLOCKS, 256, 0, stream>>>((const float4*)x, (const float4*)scale,
                                              (const float4*)inv, (float4*)out);
}

// Round 9
// 139.975 us; speedup vs baseline: 1.2219x; 1.2219x over previous
//
#include <hip/hip_runtime.h>
#include <stdint.h>

#define N_COLS 8192
#define N_ROWS 8192
#define C4 (N_COLS / 4)
#define FP8_MAX_F 448.0f
#define EPS_F 1e-12f
#define ROWCHUNKS 128
#define ROWS_PER_BLOCK (N_ROWS / ROWCHUNKS)   // 64

typedef float floatx4 __attribute__((ext_vector_type(4)));   // native vec for nt-store

// ---------------------------------------------------------------------------
// Pass 1: per-(rowchunk, column) partial abs-max. No atomics, no init needed.
// grid (8, 128) x 256 threads; each thread owns 4 columns x 64 rows.
// (Round-4 known-good structure.)
// ---------------------------------------------------------------------------
__global__ __launch_bounds__(256) void col_amax_partial(const float4* __restrict__ x4,
                                                        float4* __restrict__ partial4) {
    int c4 = blockIdx.x * 256 + threadIdx.x;
    const float4* p = x4 + (size_t)blockIdx.y * ROWS_PER_BLOCK * C4 + c4;
    uint32_t m0 = 0, m1 = 0, m2 = 0, m3 = 0;   // |x| bit-pattern max == float max
#pragma unroll 8
    for (int r = 0; r < ROWS_PER_BLOCK; ++r) {
        float4 v = p[(size_t)r * C4];
        m0 = max(m0, __float_as_uint(v.x) & 0x7FFFFFFFu);
        m1 = max(m1, __float_as_uint(v.y) & 0x7FFFFFFFu);
        m2 = max(m2, __float_as_uint(v.z) & 0x7FFFFFFFu);
        m3 = max(m3, __float_as_uint(v.w) & 0x7FFFFFFFu);
    }
    float4 o;
    o.x = __uint_as_float(m0);
    o.y = __uint_as_float(m1);
    o.z = __uint_as_float(m2);
    o.w = __uint_as_float(m3);
    partial4[(size_t)blockIdx.y * C4 + c4] = o;
}

// ---------------------------------------------------------------------------
// Pass 2: reduce 128 partials per column; emit bit-exact forward scale
// (IEEE 448/amax, matches numpy) and the dequant inverse (amax/448).
// ---------------------------------------------------------------------------
__global__ __launch_bounds__(256) void scale_from_partials(const float* __restrict__ partial,
                                                           float* __restrict__ scale,
                                                           float* __restrict__ inv) {
    int c = blockIdx.x * 256 + threadIdx.x;
    float a = 0.0f;
#pragma unroll 8
    for (int k = 0; k < ROWCHUNKS; ++k)
        a = fmaxf(a, partial[(size_t)k * N_COLS + c]);
    a = fmaxf(a, EPS_F);
    scale[c] = FP8_MAX_F / a;   // IEEE divide: must be bit-identical to numpy
    inv[c]   = a / FP8_MAX_F;   // dequant multiplier (1-2 ulp vs q/scale: fine)
}

// ---------------------------------------------------------------------------
// Pass 3: scale -> clip -> HW e4m3fn RNE cast -> dequant-multiply.
// ONE change vs round 4 (149.2 us): LOOP-FREE dispatch — one float4 per
// thread, 65536 blocks (memcpy-style: independent load->store chains,
// block turnover does the pipelining). nt-store kept (isolated +22 us, r8).
// ---------------------------------------------------------------------------
__global__ __launch_bounds__(256) void quant_kernel(const float4* __restrict__ x4,
                                                    const float4* __restrict__ scale4,
                                                    const float4* __restrict__ inv4,
                                                    floatx4* __restrict__ out4) {
    size_t i = (size_t)blockIdx.x * 256 + threadIdx.x;
    int ci = (int)(i & (size_t)(C4 - 1));
    float4 s = scale4[ci];
    float4 w = inv4[ci];
    float4 v = x4[i];
    float a0 = fminf(fmaxf(v.x * s.x, -FP8_MAX_F), FP8_MAX_F);
    float a1 = fminf(fmaxf(v.y * s.y, -FP8_MAX_F), FP8_MAX_F);
    float a2 = fminf(fmaxf(v.z * s.z, -FP8_MAX_F), FP8_MAX_F);
    float a3 = fminf(fmaxf(v.w * s.w, -FP8_MAX_F), FP8_MAX_F);
    int p = __builtin_amdgcn_cvt_pk_fp8_f32(a0, a1, 0, false);
    p = __builtin_amdgcn_cvt_pk_fp8_f32(a2, a3, p, true);
    floatx4 o;
    o.x = __builtin_amdgcn_cvt_f32_fp8(p, 0) * w.x;
    o.y = __builtin_amdgcn_cvt_f32_fp8(p, 1) * w.y;
    o.z = __builtin_amdgcn_cvt_f32_fp8(p, 2) * w.z;
    o.w = __builtin_amdgcn_cvt_f32_fp8(p, 3) * w.w;
    __builtin_nontemporal_store(o, &out4[i]);
}

extern "C" void kernel_launch(void* const* d_in, const int* in_sizes, int n_in,
                              void* d_out, int out_size, void* d_ws, size_t ws_size,
                              hipStream_t stream) {
    const float* x = (const float*)d_in[0];
    float* out = (float*)d_out;
    // ws: partial (128*8192 f32 = 4 MB) | scale (32 KB) | inv (32 KB)
    float* partial = (float*)d_ws;
    float* scale = (float*)((char*)d_ws + (size_t)ROWCHUNKS * N_COLS * sizeof(float));
    float* inv = scale + N_COLS;

    dim3 g1(N_COLS / 1024, ROWCHUNKS);
    col_amax_partial<<<g1, 256, 0, stream>>>((const float4*)x, (float4*)partial);

    scale_from_partials<<<N_COLS / 256, 256, 0, stream>>>(partial, scale, inv);

    const int n4 = N_ROWS * C4;                       // 16,777,216 float4s
    quant_kernel<<<n4 / 256, 256, 0, stream>>>((const float4*)x, (const float4*)scale,
                                               (const float4*)inv, (floatx4*)out);
}

// Round 10
// 139.588 us; speedup vs baseline: 1.2253x; 1.0028x over previous
//
#include <hip/hip_runtime.h>
#include <stdint.h>

#define N_COLS 8192
#define N_ROWS 8192
#define C4 (N_COLS / 4)
#define FP8_MAX_F 448.0f
#define EPS_F 1e-12f
#define ROWCHUNKS 128
#define ROWS_PER_BLOCK (N_ROWS / ROWCHUNKS)   // 64

typedef float floatx4 __attribute__((ext_vector_type(4)));   // native vec for nt-store

// ---------------------------------------------------------------------------
// Pass 1: per-(rowchunk, column) partial abs-max. No atomics, no init needed.
// grid (8, 128) x 256 threads; each thread owns 4 columns x 64 rows.
// (Round-4 known-good structure, ~37 us — at fill rate.)
// ---------------------------------------------------------------------------
__global__ __launch_bounds__(256) void col_amax_partial(const float4* __restrict__ x4,
                                                        float4* __restrict__ partial4) {
    int c4 = blockIdx.x * 256 + threadIdx.x;
    const float4* p = x4 + (size_t)blockIdx.y * ROWS_PER_BLOCK * C4 + c4;
    uint32_t m0 = 0, m1 = 0, m2 = 0, m3 = 0;   // |x| bit-pattern max == float max
#pragma unroll 8
    for (int r = 0; r < ROWS_PER_BLOCK; ++r) {
        float4 v = p[(size_t)r * C4];
        m0 = max(m0, __float_as_uint(v.x) & 0x7FFFFFFFu);
        m1 = max(m1, __float_as_uint(v.y) & 0x7FFFFFFFu);
        m2 = max(m2, __float_as_uint(v.z) & 0x7FFFFFFFu);
        m3 = max(m3, __float_as_uint(v.w) & 0x7FFFFFFFu);
    }
    float4 o;
    o.x = __uint_as_float(m0);
    o.y = __uint_as_float(m1);
    o.z = __uint_as_float(m2);
    o.w = __uint_as_float(m3);
    partial4[(size_t)blockIdx.y * C4 + c4] = o;
}

// ---------------------------------------------------------------------------
// Pass 2: reduce 128 partials per column; emit bit-exact forward scale
// (IEEE 448/amax, matches numpy). inv array ELIMINATED (r10 change):
// pass 3 derives the dequant multiplier via v_rcp_f32.
// ---------------------------------------------------------------------------
__global__ __launch_bounds__(256) void scale_from_partials(const float* __restrict__ partial,
                                                           float* __restrict__ scale) {
    int c = blockIdx.x * 256 + threadIdx.x;
    float a = 0.0f;
#pragma unroll 8
    for (int k = 0; k < ROWCHUNKS; ++k)
        a = fmaxf(a, partial[(size_t)k * N_COLS + c]);
    a = fmaxf(a, EPS_F);
    scale[c] = FP8_MAX_F / a;   // IEEE divide: must be bit-identical to numpy
}

// ---------------------------------------------------------------------------
// Pass 3: scale -> clip -> HW e4m3fn RNE cast -> dequant-multiply.
// ONE change vs round 9 (140.0 us): the inv4 load (16 B/thread, 256 MB of
// aggregate L2 traffic) is replaced by w = v_rcp_f32(s) on the idle TRANS
// pipe (~1 ulp; dequant tolerance is 0.108, rcp error ~1e-6). Forward
// quantization path unchanged -> bit-exact. Loop-free + nt-store kept.
// ---------------------------------------------------------------------------
__global__ __launch_bounds__(256) void quant_kernel(const float4* __restrict__ x4,
                                                    const float4* __restrict__ scale4,
                                                    floatx4* __restrict__ out4) {
    size_t i = (size_t)blockIdx.x * 256 + threadIdx.x;
    int ci = (int)(i & (size_t)(C4 - 1));
    float4 s = scale4[ci];
    float4 v = x4[i];
    float a0 = fminf(fmaxf(v.x * s.x, -FP8_MAX_F), FP8_MAX_F);
    float a1 = fminf(fmaxf(v.y * s.y, -FP8_MAX_F), FP8_MAX_F);
    float a2 = fminf(fmaxf(v.z * s.z, -FP8_MAX_F), FP8_MAX_F);
    float a3 = fminf(fmaxf(v.w * s.w, -FP8_MAX_F), FP8_MAX_F);
    int p = __builtin_amdgcn_cvt_pk_fp8_f32(a0, a1, 0, false);
    p = __builtin_amdgcn_cvt_pk_fp8_f32(a2, a3, p, true);
    floatx4 o;
    o.x = __builtin_amdgcn_cvt_f32_fp8(p, 0) * __builtin_amdgcn_rcpf(s.x);
    o.y = __builtin_amdgcn_cvt_f32_fp8(p, 1) * __builtin_amdgcn_rcpf(s.y);
    o.z = __builtin_amdgcn_cvt_f32_fp8(p, 2) * __builtin_amdgcn_rcpf(s.z);
    o.w = __builtin_amdgcn_cvt_f32_fp8(p, 3) * __builtin_amdgcn_rcpf(s.w);
    __builtin_nontemporal_store(o, &out4[i]);
}

extern "C" void kernel_launch(void* const* d_in, const int* in_sizes, int n_in,
                              void* d_out, int out_size, void* d_ws, size_t ws_size,
                              hipStream_t stream) {
    const float* x = (const float*)d_in[0];
    float* out = (float*)d_out;
    // ws: partial (128*8192 f32 = 4 MB) | scale (32 KB)
    float* partial = (float*)d_ws;
    float* scale = (float*)((char*)d_ws + (size_t)ROWCHUNKS * N_COLS * sizeof(float));

    dim3 g1(N_COLS / 1024, ROWCHUNKS);
    col_amax_partial<<<g1, 256, 0, stream>>>((const float4*)x, (float4*)partial);

    scale_from_partials<<<N_COLS / 256, 256, 0, stream>>>(partial, scale);

    const int n4 = N_ROWS * C4;                       // 16,777,216 float4s
    quant_kernel<<<n4 / 256, 256, 0, stream>>>((const float4*)x, (const float4*)scale,
                                               (floatx4*)out);
}